// Round 1
// baseline (19926.062 us; speedup 1.0000x reference)
//
#include <hip/hip_runtime.h>
#include <cstdint>
#include <cstddef>

// Problem constants (T, B, I, H, L) = (2048, 64, 256, 256, 2)
#define T_STEPS 2048
#define BB 64
#define II 256
#define HH 256
#define GG 1024  // 4*H gate rows

typedef _Float16 half2_t __attribute__((ext_vector_type(2)));
typedef _Float16 half4_t __attribute__((ext_vector_type(4)));
typedef _Float16 half8_t __attribute__((ext_vector_type(8)));
typedef float    f32x4_t __attribute__((ext_vector_type(4)));

static __device__ __forceinline__ float sigm(float x) {
    return 1.0f / (1.0f + __expf(-x));
}
// tanh via exp2-based expf; stable at +/-inf (1 - 2/(e+1): e->inf => 1, e->0 => -1)
static __device__ __forceinline__ float tanhfast(float x) {
    float e = __expf(2.0f * x);
    return 1.0f - 2.0f / (e + 1.0f);
}

// ---------------- conversion / packing kernels (all tiny) ----------------

// f32 -> f16, 4 elems/thread, n divisible by 4
__global__ void k_f32_to_f16(const float* __restrict__ in, _Float16* __restrict__ out, int n) {
    int i = (blockIdx.x * blockDim.x + threadIdx.x) * 4;
    if (i >= n) return;
    float4 v = *(const float4*)(in + i);
    half4_t h = { (_Float16)v.x, (_Float16)v.y, (_Float16)v.z, (_Float16)v.w };
    *(half4_t*)(out + i) = h;
}

// W_hh (1024 x 256 f32, row-major) -> transposed f16-pair layout:
// uint4 array indexed [p4 * 1024 + row], component c = packed pair (W[row][2p], W[row][2p+1])
// with p = 4*p4 + c.  So a thread owning `row` reads coalesced uint4s at stride 1024.
__global__ void k_pack_whh(const float* __restrict__ W, unsigned* __restrict__ wt) {
    int p = blockIdx.x;      // 0..127 (k-pair index)
    int row = threadIdx.x;   // 0..1023 (gate row)
    float2 v = *(const float2*)(W + (size_t)row * HH + 2 * p);
    union { unsigned u; half2_t h; } cv;
    cv.h = half2_t{ (_Float16)v.x, (_Float16)v.y };
    wt[((size_t)(p >> 2) * 1024 + row) * 4 + (p & 3)] = cv.u;
}

__global__ void k_bias_sum(const float* __restrict__ a, const float* __restrict__ b,
                           float* __restrict__ o) {
    int i = threadIdx.x;  // 1024 threads, 1 block
    o[i] = a[i] + b[i];
}

// ---------------- input-projection GEMM ----------------
// C[m][g] = sum_k A[m][k] * W[g][k] + bsum[g]
// A: (M=131072, 256) f32 (converted to f16 in-register), W: (1024, 256) f16 row-major.
// MFMA 16x16x32_f16; verified gfx950 layouts:
//   A-frag: lane holds A[m=lane&15][k = (lane>>4)*8 + j]  (contiguous 16B from row)
//   B-frag: lane holds B[k][n=lane&15] = W[n][k]          (contiguous 16B from W row)
//   D-frag: lane holds D[row=(lane>>4)*4 + r][col=lane&15]
// Wave computes a 64x64 tile (4x4 frags); block = 4 waves = 128x128.
// Grid = (8 nBlks, 1024 mBlks): x-fastest => the 8 blocks sharing an A-tile run
// together, so A streams from HBM once (not 8x).
template<bool XGF>
__global__ __launch_bounds__(256)
void k_gemm_xg(const float* __restrict__ A,
               const _Float16* __restrict__ W,
               const float* __restrict__ bsum,
               void* __restrict__ C) {
    const int K = II;
    int nBlk = blockIdx.x;          // 0..7
    int mBlk = blockIdx.y;          // 0..1023
    int wave = threadIdx.x >> 6;
    int lane = threadIdx.x & 63;
    int l15 = lane & 15, q = lane >> 4;
    int m0 = mBlk * 128 + (wave >> 1) * 64;
    int n0 = nBlk * 128 + (wave & 1) * 64;

    f32x4_t acc[4][4] = {};
    const float*    Ap = A + (size_t)(m0 + l15) * K + q * 8;
    const _Float16* Wp = W + (size_t)(n0 + l15) * K + q * 8;

    for (int k0 = 0; k0 < K; k0 += 32) {
        half8_t a[4], b[4];
#pragma unroll
        for (int i = 0; i < 4; i++) {
            const float* p = Ap + (size_t)i * 16 * K + k0;
            float4 u = *(const float4*)p;
            float4 v = *(const float4*)(p + 4);
            a[i] = half8_t{ (_Float16)u.x, (_Float16)u.y, (_Float16)u.z, (_Float16)u.w,
                            (_Float16)v.x, (_Float16)v.y, (_Float16)v.z, (_Float16)v.w };
        }
#pragma unroll
        for (int j = 0; j < 4; j++)
            b[j] = *(const half8_t*)(Wp + (size_t)j * 16 * K + k0);
#pragma unroll
        for (int i = 0; i < 4; i++)
#pragma unroll
            for (int j = 0; j < 4; j++)
                acc[i][j] = __builtin_amdgcn_mfma_f32_16x16x32_f16(a[i], b[j], acc[i][j], 0, 0, 0);
    }

#pragma unroll
    for (int j = 0; j < 4; j++) {
        int col = n0 + j * 16 + l15;
        float bs = bsum[col];
#pragma unroll
        for (int i = 0; i < 4; i++) {
            int row = m0 + i * 16 + q * 4;
#pragma unroll
            for (int r = 0; r < 4; r++) {
                float v = acc[i][j][r] + bs;
                size_t idx = (size_t)(row + r) * GG + col;
                if (XGF) ((float*)C)[idx] = v;
                else     ((_Float16*)C)[idx] = (_Float16)v;
            }
        }
    }
}

// ---------------- LSTM recurrence ----------------
// One 1024-thread workgroup per batch element (64 WGs, no inter-WG sync).
// Thread tid owns gate-row tid: acc = xg[t,b,tid] + dot(W_hh[tid,:], h).
// W_hh streamed from L2 (f16 pairs, transposed layout => coalesced uint4 loads).
// h broadcast from LDS via ds_read_b128 (uniform address => conflict-free).
// 4 accumulators break the fdot2 dependency chain.
// State h,c kept in f32 (hp/cp registers of threads 0..255); h also mirrored
// to LDS as f16 for the next step's matvec.
template<bool XGF>
__global__ __launch_bounds__(1024)
void k_lstm(const void* __restrict__ xg,
            const uint4* __restrict__ w4,    // 32*1024 uint4 (f16-pair transposed W_hh)
            const float* __restrict__ mask,  // (T,B)
            const float* __restrict__ reset, // (T,B)
            float* __restrict__ out,         // (T,B,H) f32
            float* __restrict__ hn,          // (B,H) slice for this layer
            float* __restrict__ cn) {
    int b = blockIdx.x, tid = threadIdx.x;
    __shared__ __align__(16) _Float16 hbuf[HH];
    __shared__ float gbuf[GG];
    if (tid < HH) hbuf[tid] = (_Float16)0.0f;
    float hp = 0.f, cp = 0.f;  // carry state (valid for tid < 256)
    __syncthreads();

    const float*    xf = (const float*)xg    + (size_t)b * GG + tid;
    const _Float16* xh = (const _Float16*)xg + (size_t)b * GG + tid;
    float xgc = XGF ? xf[0] : (float)xh[0];
    const uint4* wp = w4 + tid;

    for (int t = 0; t < T_STEPS; ++t) {
        // prefetch next step's xg so its latency hides under the matvec
        float xgn = 0.f;
        if (t + 1 < T_STEPS)
            xgn = XGF ? xf[(size_t)(t + 1) * (BB * GG)] : (float)xh[(size_t)(t + 1) * (BB * GG)];

        float a0 = xgc, a1 = 0.f, a2 = 0.f, a3 = 0.f;
#pragma unroll 8
        for (int p4 = 0; p4 < 32; ++p4) {
            uint4 w  = wp[(size_t)p4 * 1024];
            uint4 hv = *(const uint4*)(hbuf + p4 * 8);
            union { unsigned u; half2_t h; } w0, w1, w2, w3, h0, h1, h2, h3;
            w0.u = w.x;  w1.u = w.y;  w2.u = w.z;  w3.u = w.w;
            h0.u = hv.x; h1.u = hv.y; h2.u = hv.z; h3.u = hv.w;
            a0 = __builtin_amdgcn_fdot2(h0.h, w0.h, a0, false);
            a1 = __builtin_amdgcn_fdot2(h1.h, w1.h, a1, false);
            a2 = __builtin_amdgcn_fdot2(h2.h, w2.h, a2, false);
            a3 = __builtin_amdgcn_fdot2(h3.h, w3.h, a3, false);
        }
        gbuf[tid] = ((a0 + a1) + (a2 + a3));
        __syncthreads();

        if (tid < HH) {
            float m = mask[(size_t)t * BB + b];
            float r = reset[(size_t)t * BB + b];
            float gi = gbuf[tid], gf = gbuf[HH + tid];
            float gg = gbuf[2 * HH + tid], go = gbuf[3 * HH + tid];
            float i_ = sigm(gi), f_ = sigm(gf), g_ = tanhfast(gg), o_ = sigm(go);
            float cnew = f_ * cp + i_ * g_;
            float hnew = o_ * tanhfast(cnew);
            float hb = hnew * m + hp * (1.f - m);
            float cb = cnew * m + cp * (1.f - m);
            out[(size_t)t * (BB * HH) + (size_t)b * HH + tid] = hb;
            hp = hb * (1.f - r);
            cp = cb * (1.f - r);
            hbuf[tid] = (_Float16)hp;
        }
        __syncthreads();
        xgc = xgn;
    }
    if (tid < HH) {
        hn[(size_t)b * HH + tid] = hp;
        cn[(size_t)b * HH + tid] = cp;
    }
}

// ---------------- host ----------------
extern "C" void kernel_launch(void* const* d_in, const int* in_sizes, int n_in,
                              void* d_out, int out_size, void* d_ws, size_t ws_size,
                              hipStream_t stream) {
    (void)in_sizes; (void)n_in; (void)out_size;
    const float* input = (const float*)d_in[0];
    const float* mask  = (const float*)d_in[1];
    const float* reset = (const float*)d_in[2];
    const float* Wih0  = (const float*)d_in[3];
    const float* Whh0  = (const float*)d_in[4];
    const float* bih0  = (const float*)d_in[5];
    const float* bhh0  = (const float*)d_in[6];
    const float* Wih1  = (const float*)d_in[7];
    const float* Whh1  = (const float*)d_in[8];
    const float* bih1  = (const float*)d_in[9];
    const float* bhh1  = (const float*)d_in[10];

    const size_t M = (size_t)T_STEPS * BB;          // 131072 rows
    const size_t xg_f32_b = M * GG * sizeof(float); // 512 MiB
    const size_t xg_f16_b = M * GG * 2;             // 256 MiB
    const size_t wih_b = (size_t)GG * II * 2;       // 512 KiB (f16)
    const size_t whh_b = (size_t)GG * HH * 2;       // 512 KiB (f16 pairs as uint)
    const size_t need_f32 = xg_f32_b + 2 * wih_b + 2 * whh_b + 2 * 4096;
    const bool xgf = (ws_size >= need_f32);         // constant per session => same work every call
    const size_t xg_b = xgf ? xg_f32_b : xg_f16_b;

    char* base = (char*)d_ws;
    void*      xg    = (void*)base;
    _Float16*  wih0h = (_Float16*)(base + xg_b);
    _Float16*  wih1h = (_Float16*)(base + xg_b + wih_b);
    unsigned*  whh0t = (unsigned*)(base + xg_b + 2 * wih_b);
    unsigned*  whh1t = (unsigned*)(base + xg_b + 2 * wih_b + whh_b);
    float*     bsum0 = (float*)(base + xg_b + 2 * wih_b + 2 * whh_b);
    float*     bsum1 = bsum0 + GG;

    float* out1 = (float*)d_out;                         // (T,B,H); also scratch for out0
    float* hn   = out1 + (size_t)T_STEPS * BB * HH;      // (2,B,H)
    float* cn   = hn + 2 * (size_t)BB * HH;              // (2,B,H)

    // weight prep (all tiny)
    k_f32_to_f16<<<dim3((GG * II) / 1024), 256, 0, stream>>>(Wih0, wih0h, GG * II);
    k_f32_to_f16<<<dim3((GG * II) / 1024), 256, 0, stream>>>(Wih1, wih1h, GG * II);
    k_pack_whh<<<dim3(HH / 2), 1024, 0, stream>>>(Whh0, whh0t);
    k_pack_whh<<<dim3(HH / 2), 1024, 0, stream>>>(Whh1, whh1t);
    k_bias_sum<<<dim3(1), GG, 0, stream>>>(bih0, bhh0, bsum0);
    k_bias_sum<<<dim3(1), GG, 0, stream>>>(bih1, bhh1, bsum1);

    dim3 ggrid(GG / 128, M / 128);  // (8, 1024), x = N-block fastest for A reuse in L2
    if (xgf) {
        k_gemm_xg<true><<<ggrid, 256, 0, stream>>>(input, wih0h, bsum0, xg);
        k_lstm<true><<<dim3(BB), 1024, 0, stream>>>(xg, (const uint4*)whh0t, mask, reset,
                                                    out1, hn, cn);
        k_gemm_xg<true><<<ggrid, 256, 0, stream>>>(out1, wih1h, bsum1, xg);
        k_lstm<true><<<dim3(BB), 1024, 0, stream>>>(xg, (const uint4*)whh1t, mask, reset,
                                                    out1, hn + BB * HH, cn + BB * HH);
    } else {
        k_gemm_xg<false><<<ggrid, 256, 0, stream>>>(input, wih0h, bsum0, xg);
        k_lstm<false><<<dim3(BB), 1024, 0, stream>>>(xg, (const uint4*)whh0t, mask, reset,
                                                     out1, hn, cn);
        k_gemm_xg<false><<<ggrid, 256, 0, stream>>>(out1, wih1h, bsum1, xg);
        k_lstm<false><<<dim3(BB), 1024, 0, stream>>>(xg, (const uint4*)whh1t, mask, reset,
                                                     out1, hn + BB * HH, cn + BB * HH);
    }
}

// Round 2
// 11107.168 us; speedup vs baseline: 1.7940x; 1.7940x over previous
//
#include <hip/hip_runtime.h>
#include <cstdint>
#include <cstddef>

// Problem constants (T, B, I, H, L) = (2048, 64, 256, 256, 2)
#define T_STEPS 2048
#define BB 64
#define II 256
#define HH 256
#define GG 1024  // 4*H gate rows

typedef _Float16 half2_t __attribute__((ext_vector_type(2)));
typedef _Float16 half4_t __attribute__((ext_vector_type(4)));
typedef _Float16 half8_t __attribute__((ext_vector_type(8)));
typedef float    f32x4_t __attribute__((ext_vector_type(4)));
typedef unsigned u32x4_t __attribute__((ext_vector_type(4)));

static __device__ __forceinline__ float sigm(float x) {
    return 1.0f / (1.0f + __expf(-x));
}
// tanh via exp; stable at +/-inf
static __device__ __forceinline__ float tanhfast(float x) {
    float e = __expf(2.0f * x);
    return 1.0f - 2.0f / (e + 1.0f);
}

static __device__ __forceinline__ float fd2(unsigned hu, unsigned wu, float acc) {
    union { unsigned u; half2_t v; } a, b;
    a.u = hu; b.u = wu;
    return __builtin_amdgcn_fdot2(a.v, b.v, acc, false);
}

// ---------------- conversion / packing kernels (all tiny) ----------------

__global__ void k_f32_to_f16(const float* __restrict__ in, _Float16* __restrict__ out, int n) {
    int i = (blockIdx.x * blockDim.x + threadIdx.x) * 4;
    if (i >= n) return;
    float4 v = *(const float4*)(in + i);
    half4_t h = { (_Float16)v.x, (_Float16)v.y, (_Float16)v.z, (_Float16)v.w };
    *(half4_t*)(out + i) = h;
}

// W_hh (1024 x 256 f32, row-major) -> transposed f16-pair layout:
// uint4 array indexed [p4 * 1024 + row], component c = packed pair (W[row][2p], W[row][2p+1])
// with p = 4*p4 + c.
__global__ void k_pack_whh(const float* __restrict__ W, unsigned* __restrict__ wt) {
    int p = blockIdx.x;      // 0..127 (k-pair index)
    int row = threadIdx.x;   // 0..1023 (gate row)
    float2 v = *(const float2*)(W + (size_t)row * HH + 2 * p);
    union { unsigned u; half2_t h; } cv;
    cv.h = half2_t{ (_Float16)v.x, (_Float16)v.y };
    wt[((size_t)(p >> 2) * 1024 + row) * 4 + (p & 3)] = cv.u;
}

__global__ void k_bias_sum(const float* __restrict__ a, const float* __restrict__ b,
                           float* __restrict__ o) {
    int i = threadIdx.x;  // 1024 threads, 1 block
    o[i] = a[i] + b[i];
}

// ---------------- input-projection GEMM (unchanged from R1, ~4% of time) ----------------
template<bool XGF>
__global__ __launch_bounds__(256)
void k_gemm_xg(const float* __restrict__ A,
               const _Float16* __restrict__ W,
               const float* __restrict__ bsum,
               void* __restrict__ C) {
    const int K = II;
    int nBlk = blockIdx.x;          // 0..7
    int mBlk = blockIdx.y;          // 0..1023
    int wave = threadIdx.x >> 6;
    int lane = threadIdx.x & 63;
    int l15 = lane & 15, q = lane >> 4;
    int m0 = mBlk * 128 + (wave >> 1) * 64;
    int n0 = nBlk * 128 + (wave & 1) * 64;

    f32x4_t acc[4][4] = {};
    const float*    Ap = A + (size_t)(m0 + l15) * K + q * 8;
    const _Float16* Wp = W + (size_t)(n0 + l15) * K + q * 8;

    for (int k0 = 0; k0 < K; k0 += 32) {
        half8_t a[4], b[4];
#pragma unroll
        for (int i = 0; i < 4; i++) {
            const float* p = Ap + (size_t)i * 16 * K + k0;
            float4 u = *(const float4*)p;
            float4 v = *(const float4*)(p + 4);
            a[i] = half8_t{ (_Float16)u.x, (_Float16)u.y, (_Float16)u.z, (_Float16)u.w,
                            (_Float16)v.x, (_Float16)v.y, (_Float16)v.z, (_Float16)v.w };
        }
#pragma unroll
        for (int j = 0; j < 4; j++)
            b[j] = *(const half8_t*)(Wp + (size_t)j * 16 * K + k0);
#pragma unroll
        for (int i = 0; i < 4; i++)
#pragma unroll
            for (int j = 0; j < 4; j++)
                acc[i][j] = __builtin_amdgcn_mfma_f32_16x16x32_f16(a[i], b[j], acc[i][j], 0, 0, 0);
    }

#pragma unroll
    for (int j = 0; j < 4; j++) {
        int col = n0 + j * 16 + l15;
        float bs = bsum[col];
#pragma unroll
        for (int i = 0; i < 4; i++) {
            int row = m0 + i * 16 + q * 4;
#pragma unroll
            for (int r = 0; r < 4; r++) {
                float v = acc[i][j][r] + bs;
                size_t idx = (size_t)(row + r) * GG + col;
                if (XGF) ((float*)C)[idx] = v;
                else     ((_Float16*)C)[idx] = (_Float16)v;
            }
        }
    }
}

// ---------------- LSTM recurrence: CU-resident weights ----------------
// One 512-thread WG (8 waves) per batch element. Thread tid owns gate rows
// {tid, tid+512}; each row's 128 f16-pairs split: quads 0..23 (96 pairs) in
// VGPRs (2 rows x 24 uint4 = 192 VGPRs), quads 24..31 (32 pairs) in LDS
// (1024 rows x 8 uint4 = 128 KiB of the 160 KiB CU LDS).  No per-step global
// weight traffic at all -- that streaming was 91% of the R1 step time.
// h broadcast from LDS (same-address b128 = free); i/g gate sums stay in the
// owning thread's registers, f/o cross over through a 2 KiB LDS buffer.
template<bool XGF>
__global__ __launch_bounds__(512, 2)
void k_lstm(const void* __restrict__ xg,
            const u32x4_t* __restrict__ w4,  // [32][1024] uint4 (f16-pair transposed W_hh)
            const float* __restrict__ mask,  // (T,B)
            const float* __restrict__ reset, // (T,B)
            float* __restrict__ out,         // (T,B,H) f32
            float* __restrict__ hn,          // (B,H) slice for this layer
            float* __restrict__ cn) {
    __shared__ __align__(16) u32x4_t wsh[8 * 1024];  // 128 KiB weight slice (quads 24..31)
    __shared__ __align__(16) _Float16 hbuf[HH];      // 512 B
    __shared__ float gbF[256];                        // f-gate sums
    __shared__ float gbO[256];                        // o-gate sums

    const int b = blockIdx.x, tid = threadIdx.x;
    const int r0 = tid, r1 = tid + 512;

    // stage LDS weight slice (coalesced; once)
#pragma unroll
    for (int j = 0; j < 8; ++j) {
        wsh[j * 1024 + r0] = w4[(24 + j) * 1024 + r0];
        wsh[j * 1024 + r1] = w4[(24 + j) * 1024 + r1];
    }
    // register-resident weight slice (quads 0..23)
    u32x4_t wr0[24], wr1[24];
#pragma unroll
    for (int j = 0; j < 24; ++j) {
        wr0[j] = w4[j * 1024 + r0];
        wr1[j] = w4[j * 1024 + r1];
    }
    if (tid < HH) hbuf[tid] = (_Float16)0.0f;
    float hp = 0.f, cp = 0.f;  // carry state (valid for tid < 256)

    const float*    xf  = (const float*)xg    + (size_t)b * GG;
    const _Float16* xh  = (const _Float16*)xg + (size_t)b * GG;
    const u32x4_t*  hsh = (const u32x4_t*)hbuf;

    float xg0 = XGF ? xf[r0] : (float)xh[r0];
    float xg1 = XGF ? xf[r1] : (float)xh[r1];
    float mc = mask[b], rc = reset[b];
    __syncthreads();

    for (int t = 0; t < T_STEPS; ++t) {
        // prefetch next step's per-thread globals (latency hides under matvec)
        float xg0n = 0.f, xg1n = 0.f, mn = 0.f, rn = 0.f;
        if (t + 1 < T_STEPS) {
            size_t o = (size_t)(t + 1) * (BB * GG);
            xg0n = XGF ? xf[o + r0] : (float)xh[o + r0];
            xg1n = XGF ? xf[o + r1] : (float)xh[o + r1];
            mn = mask[(size_t)(t + 1) * BB + b];
            rn = reset[(size_t)(t + 1) * BB + b];
        }

        float a00 = xg0, a01 = 0.f, a02 = 0.f, a03 = 0.f;
        float a10 = xg1, a11 = 0.f, a12 = 0.f, a13 = 0.f;
#pragma unroll
        for (int j = 0; j < 24; ++j) {
            u32x4_t hv = hsh[j];  // broadcast (same addr across wave)
            a00 = fd2(hv.x, wr0[j].x, a00);
            a01 = fd2(hv.y, wr0[j].y, a01);
            a02 = fd2(hv.z, wr0[j].z, a02);
            a03 = fd2(hv.w, wr0[j].w, a03);
            a10 = fd2(hv.x, wr1[j].x, a10);
            a11 = fd2(hv.y, wr1[j].y, a11);
            a12 = fd2(hv.z, wr1[j].z, a12);
            a13 = fd2(hv.w, wr1[j].w, a13);
        }
#pragma unroll
        for (int j = 0; j < 8; ++j) {
            u32x4_t hv = hsh[24 + j];
            u32x4_t w0 = wsh[j * 1024 + r0];  // consecutive lanes -> conflict-free
            u32x4_t w1 = wsh[j * 1024 + r1];
            a00 = fd2(hv.x, w0.x, a00);
            a01 = fd2(hv.y, w0.y, a01);
            a02 = fd2(hv.z, w0.z, a02);
            a03 = fd2(hv.w, w0.w, a03);
            a10 = fd2(hv.x, w1.x, a10);
            a11 = fd2(hv.y, w1.y, a11);
            a12 = fd2(hv.z, w1.z, a12);
            a13 = fd2(hv.w, w1.w, a13);
        }
        float s0 = (a00 + a01) + (a02 + a03);  // row r0: i (tid<256) or f
        float s1 = (a10 + a11) + (a12 + a13);  // row r1: g (tid<256) or o
        if (tid >= 256) { gbF[tid - 256] = s0; gbO[tid - 256] = s1; }
        __syncthreads();

        if (tid < 256) {
            float i_ = sigm(s0), g_ = tanhfast(s1);
            float f_ = sigm(gbF[tid]), o_ = sigm(gbO[tid]);
            float cnew = f_ * cp + i_ * g_;
            float hnew = o_ * tanhfast(cnew);
            float hb = hnew * mc + hp * (1.f - mc);
            float cb = cnew * mc + cp * (1.f - mc);
            out[(size_t)t * (BB * HH) + (size_t)b * HH + tid] = hb;
            hp = hb * (1.f - rc);
            cp = cb * (1.f - rc);
            hbuf[tid] = (_Float16)hp;
        }
        __syncthreads();
        xg0 = xg0n; xg1 = xg1n; mc = mn; rc = rn;
    }
    if (tid < 256) {
        hn[(size_t)b * HH + tid] = hp;
        cn[(size_t)b * HH + tid] = cp;
    }
}

// ---------------- host ----------------
extern "C" void kernel_launch(void* const* d_in, const int* in_sizes, int n_in,
                              void* d_out, int out_size, void* d_ws, size_t ws_size,
                              hipStream_t stream) {
    (void)in_sizes; (void)n_in; (void)out_size;
    const float* input = (const float*)d_in[0];
    const float* mask  = (const float*)d_in[1];
    const float* reset = (const float*)d_in[2];
    const float* Wih0  = (const float*)d_in[3];
    const float* Whh0  = (const float*)d_in[4];
    const float* bih0  = (const float*)d_in[5];
    const float* bhh0  = (const float*)d_in[6];
    const float* Wih1  = (const float*)d_in[7];
    const float* Whh1  = (const float*)d_in[8];
    const float* bih1  = (const float*)d_in[9];
    const float* bhh1  = (const float*)d_in[10];

    const size_t M = (size_t)T_STEPS * BB;          // 131072 rows
    const size_t xg_f32_b = M * GG * sizeof(float); // 512 MiB
    const size_t xg_f16_b = M * GG * 2;             // 256 MiB
    const size_t wih_b = (size_t)GG * II * 2;       // 512 KiB (f16)
    const size_t whh_b = (size_t)GG * HH * 2;       // 512 KiB (f16 pairs)
    const size_t need_f32 = xg_f32_b + 2 * wih_b + 2 * whh_b + 2 * 4096;
    const bool xgf = (ws_size >= need_f32);
    const size_t xg_b = xgf ? xg_f32_b : xg_f16_b;

    char* base = (char*)d_ws;
    void*      xg    = (void*)base;
    _Float16*  wih0h = (_Float16*)(base + xg_b);
    _Float16*  wih1h = (_Float16*)(base + xg_b + wih_b);
    unsigned*  whh0t = (unsigned*)(base + xg_b + 2 * wih_b);
    unsigned*  whh1t = (unsigned*)(base + xg_b + 2 * wih_b + whh_b);
    float*     bsum0 = (float*)(base + xg_b + 2 * wih_b + 2 * whh_b);
    float*     bsum1 = bsum0 + GG;

    float* out1 = (float*)d_out;                         // (T,B,H); also scratch for out0
    float* hn   = out1 + (size_t)T_STEPS * BB * HH;      // (2,B,H)
    float* cn   = hn + 2 * (size_t)BB * HH;              // (2,B,H)

    // weight prep (all tiny)
    k_f32_to_f16<<<dim3((GG * II) / 1024), 256, 0, stream>>>(Wih0, wih0h, GG * II);
    k_f32_to_f16<<<dim3((GG * II) / 1024), 256, 0, stream>>>(Wih1, wih1h, GG * II);
    k_pack_whh<<<dim3(HH / 2), 1024, 0, stream>>>(Whh0, whh0t);
    k_pack_whh<<<dim3(HH / 2), 1024, 0, stream>>>(Whh1, whh1t);
    k_bias_sum<<<dim3(1), GG, 0, stream>>>(bih0, bhh0, bsum0);
    k_bias_sum<<<dim3(1), GG, 0, stream>>>(bih1, bhh1, bsum1);

    dim3 ggrid(GG / 128, M / 128);  // (8, 1024)
    if (xgf) {
        k_gemm_xg<true><<<ggrid, 256, 0, stream>>>(input, wih0h, bsum0, xg);
        k_lstm<true><<<dim3(BB), 512, 0, stream>>>(xg, (const u32x4_t*)whh0t, mask, reset,
                                                   out1, hn, cn);
        k_gemm_xg<true><<<ggrid, 256, 0, stream>>>(out1, wih1h, bsum1, xg);
        k_lstm<true><<<dim3(BB), 512, 0, stream>>>(xg, (const u32x4_t*)whh1t, mask, reset,
                                                   out1, hn + BB * HH, cn + BB * HH);
    } else {
        k_gemm_xg<false><<<ggrid, 256, 0, stream>>>(input, wih0h, bsum0, xg);
        k_lstm<false><<<dim3(BB), 512, 0, stream>>>(xg, (const u32x4_t*)whh0t, mask, reset,
                                                    out1, hn, cn);
        k_gemm_xg<false><<<ggrid, 256, 0, stream>>>(out1, wih1h, bsum1, xg);
        k_lstm<false><<<dim3(BB), 512, 0, stream>>>(xg, (const u32x4_t*)whh1t, mask, reset,
                                                    out1, hn + BB * HH, cn + BB * HH);
    }
}

// Round 3
// 11061.932 us; speedup vs baseline: 1.8013x; 1.0041x over previous
//
#include <hip/hip_runtime.h>
#include <cstdint>
#include <cstddef>

// Problem constants (T, B, I, H, L) = (2048, 64, 256, 256, 2)
#define T_STEPS 2048
#define BB 64
#define II 256
#define HH 256
#define GG 1024  // 4*H gate rows

typedef _Float16 half2_t __attribute__((ext_vector_type(2)));
typedef _Float16 half4_t __attribute__((ext_vector_type(4)));
typedef _Float16 half8_t __attribute__((ext_vector_type(8)));
typedef float    f32x4_t __attribute__((ext_vector_type(4)));
typedef unsigned u32x4_t __attribute__((ext_vector_type(4)));

static __device__ __forceinline__ float sigm(float x) {
    return 1.0f / (1.0f + __expf(-x));
}
// tanh via exp; stable at +/-inf
static __device__ __forceinline__ float tanhfast(float x) {
    float e = __expf(2.0f * x);
    return 1.0f - 2.0f / (e + 1.0f);
}

static __device__ __forceinline__ float fd2(unsigned hu, unsigned wu, float acc) {
    union { unsigned u; half2_t v; } a, b;
    a.u = hu; b.u = wu;
    return __builtin_amdgcn_fdot2(a.v, b.v, acc, false);
}

// ---------------- conversion / packing kernels (all tiny) ----------------

__global__ void k_f32_to_f16(const float* __restrict__ in, _Float16* __restrict__ out, int n) {
    int i = (blockIdx.x * blockDim.x + threadIdx.x) * 4;
    if (i >= n) return;
    float4 v = *(const float4*)(in + i);
    half4_t h = { (_Float16)v.x, (_Float16)v.y, (_Float16)v.z, (_Float16)v.w };
    *(half4_t*)(out + i) = h;
}

// W_hh (1024 x 256 f32, row-major) -> transposed f16-pair layout:
// uint4 array indexed [p4 * 1024 + row], component c = packed pair (W[row][2p], W[row][2p+1])
// with p = 4*p4 + c.
__global__ void k_pack_whh(const float* __restrict__ W, unsigned* __restrict__ wt) {
    int p = blockIdx.x;      // 0..127 (k-pair index)
    int row = threadIdx.x;   // 0..1023 (gate row)
    float2 v = *(const float2*)(W + (size_t)row * HH + 2 * p);
    union { unsigned u; half2_t h; } cv;
    cv.h = half2_t{ (_Float16)v.x, (_Float16)v.y };
    wt[((size_t)(p >> 2) * 1024 + row) * 4 + (p & 3)] = cv.u;
}

__global__ void k_bias_sum(const float* __restrict__ a, const float* __restrict__ b,
                           float* __restrict__ o) {
    int i = threadIdx.x;  // 1024 threads, 1 block
    o[i] = a[i] + b[i];
}

// ---------------- input-projection GEMM (unchanged, ~4% of time) ----------------
template<bool XGF>
__global__ __launch_bounds__(256)
void k_gemm_xg(const float* __restrict__ A,
               const _Float16* __restrict__ W,
               const float* __restrict__ bsum,
               void* __restrict__ C) {
    const int K = II;
    int nBlk = blockIdx.x;          // 0..7
    int mBlk = blockIdx.y;          // 0..1023
    int wave = threadIdx.x >> 6;
    int lane = threadIdx.x & 63;
    int l15 = lane & 15, q = lane >> 4;
    int m0 = mBlk * 128 + (wave >> 1) * 64;
    int n0 = nBlk * 128 + (wave & 1) * 64;

    f32x4_t acc[4][4] = {};
    const float*    Ap = A + (size_t)(m0 + l15) * K + q * 8;
    const _Float16* Wp = W + (size_t)(n0 + l15) * K + q * 8;

    for (int k0 = 0; k0 < K; k0 += 32) {
        half8_t a[4], b[4];
#pragma unroll
        for (int i = 0; i < 4; i++) {
            const float* p = Ap + (size_t)i * 16 * K + k0;
            float4 u = *(const float4*)p;
            float4 v = *(const float4*)(p + 4);
            a[i] = half8_t{ (_Float16)u.x, (_Float16)u.y, (_Float16)u.z, (_Float16)u.w,
                            (_Float16)v.x, (_Float16)v.y, (_Float16)v.z, (_Float16)v.w };
        }
#pragma unroll
        for (int j = 0; j < 4; j++)
            b[j] = *(const half8_t*)(Wp + (size_t)j * 16 * K + k0);
#pragma unroll
        for (int i = 0; i < 4; i++)
#pragma unroll
            for (int j = 0; j < 4; j++)
                acc[i][j] = __builtin_amdgcn_mfma_f32_16x16x32_f16(a[i], b[j], acc[i][j], 0, 0, 0);
    }

#pragma unroll
    for (int j = 0; j < 4; j++) {
        int col = n0 + j * 16 + l15;
        float bs = bsum[col];
#pragma unroll
        for (int i = 0; i < 4; i++) {
            int row = m0 + i * 16 + q * 4;
#pragma unroll
            for (int r = 0; r < 4; r++) {
                float v = acc[i][j][r] + bs;
                size_t idx = (size_t)(row + r) * GG + col;
                if (XGF) ((float*)C)[idx] = v;
                else     ((_Float16*)C)[idx] = (_Float16)v;
            }
        }
    }
}

// ---------------- LSTM recurrence: CU-resident weights ----------------
// One 512-thread WG (8 waves) per batch element. Thread tid owns gate rows
// {tid, tid+512}. Per row: 128 f16-pairs. Quads 0..23 (96 pairs) live in
// VGPRs -- 2 rows x 24 uint4 = 192 VGPRs; quads 24..31 in LDS (128 KiB).
//
// R2 lesson: __launch_bounds__(512,2) only sets a MIN waves/EU; the backend
// still targeted 4 waves/EU (128 VGPRs) and rematerialized the weight loads
// inside the t-loop (per-step L2 streaming, VGPR_Count=128). Fix:
//   - amdgpu_waves_per_eu(2,2) pins the budget at 256 VGPRs/thread
//     (8 waves x 256 = the whole 512 KB/CU unified file, 1 WG/CU), and
//   - an empty asm fence on every weight dword makes the value opaque so
//     the allocator cannot re-load it from global.
template<bool XGF>
__global__ __launch_bounds__(512)
__attribute__((amdgpu_waves_per_eu(2, 2)))
void k_lstm(const void* __restrict__ xg,
            const u32x4_t* __restrict__ w4,  // [32][1024] uint4 (f16-pair transposed W_hh)
            const float* __restrict__ mask,  // (T,B)
            const float* __restrict__ reset, // (T,B)
            float* __restrict__ out,         // (T,B,H) f32
            float* __restrict__ hn,          // (B,H) slice for this layer
            float* __restrict__ cn) {
    __shared__ __align__(16) u32x4_t wsh[8 * 1024];  // 128 KiB weight slice (quads 24..31)
    __shared__ __align__(16) _Float16 hbuf[HH];      // 512 B
    __shared__ float gbF[256];                        // sigm(f-gate) crossover
    __shared__ float gbO[256];                        // sigm(o-gate) crossover

    const int b = blockIdx.x, tid = threadIdx.x;
    const int r0 = tid, r1 = tid + 512;

    // stage LDS weight slice (coalesced; once)
#pragma unroll
    for (int j = 0; j < 8; ++j) {
        wsh[j * 1024 + r0] = w4[(24 + j) * 1024 + r0];
        wsh[j * 1024 + r1] = w4[(24 + j) * 1024 + r1];
    }
    // register-resident weight slice (quads 0..23), pinned via asm fences
    unsigned wr0[96], wr1[96];
#pragma unroll
    for (int j = 0; j < 24; ++j) {
        u32x4_t a = w4[j * 1024 + r0];
        u32x4_t c = w4[j * 1024 + r1];
        wr0[4 * j + 0] = a.x; wr0[4 * j + 1] = a.y; wr0[4 * j + 2] = a.z; wr0[4 * j + 3] = a.w;
        wr1[4 * j + 0] = c.x; wr1[4 * j + 1] = c.y; wr1[4 * j + 2] = c.z; wr1[4 * j + 3] = c.w;
    }
#pragma unroll
    for (int j = 0; j < 96; ++j) {
        asm volatile("" : "+v"(wr0[j]));
        asm volatile("" : "+v"(wr1[j]));
    }

    if (tid < HH) hbuf[tid] = (_Float16)0.0f;
    float hp = 0.f, cp = 0.f;  // carry state (valid for tid < 256)

    const float*    xf  = (const float*)xg    + (size_t)b * GG;
    const _Float16* xh  = (const _Float16*)xg + (size_t)b * GG;
    const u32x4_t*  hsh = (const u32x4_t*)hbuf;

    float xg0 = XGF ? xf[r0] : (float)xh[r0];
    float xg1 = XGF ? xf[r1] : (float)xh[r1];
    float mc = mask[b], rc = reset[b];
    __syncthreads();

    for (int t = 0; t < T_STEPS; ++t) {
        // prefetch next step's per-thread globals (latency hides under matvec)
        float xg0n = 0.f, xg1n = 0.f, mn = 0.f, rn = 0.f;
        if (t + 1 < T_STEPS) {
            size_t o = (size_t)(t + 1) * (BB * GG);
            xg0n = XGF ? xf[o + r0] : (float)xh[o + r0];
            xg1n = XGF ? xf[o + r1] : (float)xh[o + r1];
            mn = mask[(size_t)(t + 1) * BB + b];
            rn = reset[(size_t)(t + 1) * BB + b];
        }

        float a00 = xg0, a01 = 0.f, a02 = 0.f, a03 = 0.f;
        float a10 = xg1, a11 = 0.f, a12 = 0.f, a13 = 0.f;
#pragma unroll
        for (int j = 0; j < 24; ++j) {
            u32x4_t hv = hsh[j];  // broadcast (same addr across wave)
            a00 = fd2(hv.x, wr0[4 * j + 0], a00);
            a01 = fd2(hv.y, wr0[4 * j + 1], a01);
            a02 = fd2(hv.z, wr0[4 * j + 2], a02);
            a03 = fd2(hv.w, wr0[4 * j + 3], a03);
            a10 = fd2(hv.x, wr1[4 * j + 0], a10);
            a11 = fd2(hv.y, wr1[4 * j + 1], a11);
            a12 = fd2(hv.z, wr1[4 * j + 2], a12);
            a13 = fd2(hv.w, wr1[4 * j + 3], a13);
        }
#pragma unroll
        for (int j = 0; j < 8; ++j) {
            u32x4_t hv = hsh[24 + j];
            u32x4_t w0 = wsh[j * 1024 + r0];  // consecutive lanes -> conflict-free
            u32x4_t w1 = wsh[j * 1024 + r1];
            a00 = fd2(hv.x, w0.x, a00);
            a01 = fd2(hv.y, w0.y, a01);
            a02 = fd2(hv.z, w0.z, a02);
            a03 = fd2(hv.w, w0.w, a03);
            a10 = fd2(hv.x, w1.x, a10);
            a11 = fd2(hv.y, w1.y, a11);
            a12 = fd2(hv.z, w1.z, a12);
            a13 = fd2(hv.w, w1.w, a13);
        }
        float s0 = (a00 + a01) + (a02 + a03);  // row r0: i (tid<256) or f
        float s1 = (a10 + a11) + (a12 + a13);  // row r1: g (tid<256) or o
        if (tid >= 256) { gbF[tid - 256] = sigm(s0); gbO[tid - 256] = sigm(s1); }
        __syncthreads();

        if (tid < 256) {
            float i_ = sigm(s0), g_ = tanhfast(s1);
            float f_ = gbF[tid], o_ = gbO[tid];
            float cnew = f_ * cp + i_ * g_;
            float hnew = o_ * tanhfast(cnew);
            float hb = hnew * mc + hp * (1.f - mc);
            float cb = cnew * mc + cp * (1.f - mc);
            out[(size_t)t * (BB * HH) + (size_t)b * HH + tid] = hb;
            hp = hb * (1.f - rc);
            cp = cb * (1.f - rc);
            hbuf[tid] = (_Float16)hp;
        }
        __syncthreads();
        xg0 = xg0n; xg1 = xg1n; mc = mn; rc = rn;
    }
    if (tid < 256) {
        hn[(size_t)b * HH + tid] = hp;
        cn[(size_t)b * HH + tid] = cp;
    }
}

// ---------------- host ----------------
extern "C" void kernel_launch(void* const* d_in, const int* in_sizes, int n_in,
                              void* d_out, int out_size, void* d_ws, size_t ws_size,
                              hipStream_t stream) {
    (void)in_sizes; (void)n_in; (void)out_size;
    const float* input = (const float*)d_in[0];
    const float* mask  = (const float*)d_in[1];
    const float* reset = (const float*)d_in[2];
    const float* Wih0  = (const float*)d_in[3];
    const float* Whh0  = (const float*)d_in[4];
    const float* bih0  = (const float*)d_in[5];
    const float* bhh0  = (const float*)d_in[6];
    const float* Wih1  = (const float*)d_in[7];
    const float* Whh1  = (const float*)d_in[8];
    const float* bih1  = (const float*)d_in[9];
    const float* bhh1  = (const float*)d_in[10];

    const size_t M = (size_t)T_STEPS * BB;          // 131072 rows
    const size_t xg_f32_b = M * GG * sizeof(float); // 512 MiB
    const size_t xg_f16_b = M * GG * 2;             // 256 MiB
    const size_t wih_b = (size_t)GG * II * 2;       // 512 KiB (f16)
    const size_t whh_b = (size_t)GG * HH * 2;       // 512 KiB (f16 pairs)
    const size_t need_f32 = xg_f32_b + 2 * wih_b + 2 * whh_b + 2 * 4096;
    const bool xgf = (ws_size >= need_f32);
    const size_t xg_b = xgf ? xg_f32_b : xg_f16_b;

    char* base = (char*)d_ws;
    void*      xg    = (void*)base;
    _Float16*  wih0h = (_Float16*)(base + xg_b);
    _Float16*  wih1h = (_Float16*)(base + xg_b + wih_b);
    unsigned*  whh0t = (unsigned*)(base + xg_b + 2 * wih_b);
    unsigned*  whh1t = (unsigned*)(base + xg_b + 2 * wih_b + whh_b);
    float*     bsum0 = (float*)(base + xg_b + 2 * wih_b + 2 * whh_b);
    float*     bsum1 = bsum0 + GG;

    float* out1 = (float*)d_out;                         // (T,B,H); also scratch for out0
    float* hn   = out1 + (size_t)T_STEPS * BB * HH;      // (2,B,H)
    float* cn   = hn + 2 * (size_t)BB * HH;              // (2,B,H)

    // weight prep (all tiny)
    k_f32_to_f16<<<dim3((GG * II) / 1024), 256, 0, stream>>>(Wih0, wih0h, GG * II);
    k_f32_to_f16<<<dim3((GG * II) / 1024), 256, 0, stream>>>(Wih1, wih1h, GG * II);
    k_pack_whh<<<dim3(HH / 2), 1024, 0, stream>>>(Whh0, whh0t);
    k_pack_whh<<<dim3(HH / 2), 1024, 0, stream>>>(Whh1, whh1t);
    k_bias_sum<<<dim3(1), GG, 0, stream>>>(bih0, bhh0, bsum0);
    k_bias_sum<<<dim3(1), GG, 0, stream>>>(bih1, bhh1, bsum1);

    dim3 ggrid(GG / 128, M / 128);  // (8, 1024)
    if (xgf) {
        k_gemm_xg<true><<<ggrid, 256, 0, stream>>>(input, wih0h, bsum0, xg);
        k_lstm<true><<<dim3(BB), 512, 0, stream>>>(xg, (const u32x4_t*)whh0t, mask, reset,
                                                   out1, hn, cn);
        k_gemm_xg<true><<<ggrid, 256, 0, stream>>>(out1, wih1h, bsum1, xg);
        k_lstm<true><<<dim3(BB), 512, 0, stream>>>(xg, (const u32x4_t*)whh1t, mask, reset,
                                                   out1, hn + BB * HH, cn + BB * HH);
    } else {
        k_gemm_xg<false><<<ggrid, 256, 0, stream>>>(input, wih0h, bsum0, xg);
        k_lstm<false><<<dim3(BB), 512, 0, stream>>>(xg, (const u32x4_t*)whh0t, mask, reset,
                                                    out1, hn, cn);
        k_gemm_xg<false><<<ggrid, 256, 0, stream>>>(out1, wih1h, bsum1, xg);
        k_lstm<false><<<dim3(BB), 512, 0, stream>>>(xg, (const u32x4_t*)whh1t, mask, reset,
                                                    out1, hn + BB * HH, cn + BB * HH);
    }
}